// Round 2
// baseline (2207.467 us; speedup 1.0000x reference)
//
#include <hip/hip_runtime.h>

// ============================================================================
// CNF log-density, fused persistent kernel — Round 1.
// Structural change vs R0: NO LDS weight staging, NO __syncthreads anywhere.
//   - B fragments loaded per-wave straight from fragment-linear bf16 weights
//     in d_ws (global_load_dwordx4, coalesced 1 KB/instr, L1/L2-resident).
//     Each B load feeds 2 MFMAs (value + tangent JVP stream).
//   - RK k-vectors stored bf16 in wave-private LDS (5 slots; k6 consumed
//     immediately) -> caller register state ~50 VGPRs, no scratch spills.
//   - Transpose scratch shrunk to half-width (4224 B/wave), two passes.
//   - LDS/block = 57,856 B; __launch_bounds__(256,2) -> 2 blocks/CU, all
//     512 blocks co-resident; waves fully independent (latency-tolerant).
// ============================================================================

#define DIM   64
#define HID   256
#define BATCH 32768
#define LOG2PI_HALF_SUM 58.8120661251f   // 32 * log(2*pi)

typedef float  floatx4 __attribute__((ext_vector_type(4)));
typedef short  short8  __attribute__((ext_vector_type(8)));

// ---- workspace layout (bytes): bf16 fragment-linear weights + fp32 biases
#define W1OFF 0          // 2 kt * 16 nt * 1KB  = 32768
#define W2OFF 32768      // 8 kt * 16 nt * 1KB  = 131072
#define W3OFF 163840     // 131072
#define W4OFF 294912     // 8 kt * 4 nt * 1KB   = 32768
#define BOFF  327680     // biases fp32: b1[256] b2[256] b3[256] b4[64]

// ---- LDS layout (bytes), per wave ----
#define TBS      132                     // shorts per row in transpose scratch
#define TBFSTR   66                      // floats per row (same 4224 B buffer)
#define TBBYTES  4224                    // 16 * 132 * 2
#define KSLOTOFF 4224                    // 5 slots x 2048 B (bf16 k storage)
#define WAVE_LDS 14464                   // 4224 + 5*2048
#define SMEM_BYTES (4 * WAVE_LDS)        // 57856

__device__ __forceinline__ short f2bf(float f) {
    union { float f; unsigned u; } v; v.f = f;
    unsigned r = v.u + 0x7FFFu + ((v.u >> 16) & 1u);   // RTNE
    return (short)(r >> 16);
}
__device__ __forceinline__ float bf2f(short s) {
    union { unsigned u; float f; } v; v.u = ((unsigned)(unsigned short)s) << 16;
    return v.f;
}

__device__ __forceinline__ float fast_tanh(float x) {
    float e = __expf(2.0f * x);
    return 1.0f - 2.0f * __builtin_amdgcn_rcpf(e + 1.0f);
}

// Hidden-layer epilogue: tanh in place on av, bf16 h -> transpose scratch
// (half-width, two passes), read back A-frags; then tangent (1-h^2)*at same
// way. Wave-private LDS: same-wave DS ordering + compiler waitcnts suffice.
__device__ __forceinline__ void act_transpose(floatx4* av, floatx4* at,
                                              short8* Av, short8* At,
                                              short* tbs, int m, int kq) {
#pragma unroll
    for (int half = 0; half < 2; half++) {
#pragma unroll
        for (int nt8 = 0; nt8 < 8; nt8++) {
            const int nt = half * 8 + nt8;
#pragma unroll
            for (int i = 0; i < 4; i++) {
                float hv = fast_tanh(av[nt][i]);
                av[nt][i] = hv;                      // keep h for tangent
                tbs[(kq * 4 + i) * TBS + nt8 * 16 + m] = f2bf(hv);
            }
        }
#pragma unroll
        for (int kt = 0; kt < 4; kt++)
            Av[half * 4 + kt] = *(const short8*)&tbs[m * TBS + kt * 32 + kq * 8];
    }
#pragma unroll
    for (int half = 0; half < 2; half++) {
#pragma unroll
        for (int nt8 = 0; nt8 < 8; nt8++) {
            const int nt = half * 8 + nt8;
#pragma unroll
            for (int i = 0; i < 4; i++) {
                float tv = (1.0f - av[nt][i] * av[nt][i]) * at[nt][i];
                tbs[(kq * 4 + i) * TBS + nt8 * 16 + m] = f2bf(tv);
            }
        }
#pragma unroll
        for (int kt = 0; kt < 4; kt++)
            At[half * 4 + kt] = *(const short8*)&tbs[m * TBS + kt * 32 + kq * 8];
    }
}

// One ODE f-eval. dz left in tbs-as-float (stride TBFSTR); returns div for
// row (lane&15), replicated across quads. B frags come straight from global.
__device__ __forceinline__ float feval(short8 z0, short8 z1, short8 e0, short8 e1,
                                       const float* ef,
                                       const char* __restrict__ ws, short* tbs) {
    const int lane = threadIdx.x & 63;
    const int m  = lane & 15, kq = lane >> 4;
    float* tbf = (float*)tbs;
    const float* bias = (const float*)(ws + BOFF);

    floatx4 av[16], at[16];
    short8  Av[8], At[8];
    const floatx4 zero4 = {0.f, 0.f, 0.f, 0.f};

    // ---------------- layer 1: K=64 (2 kt), N=256 ----------------
    {
        const short8* wb = (const short8*)(ws + W1OFF);
#pragma unroll
        for (int nt = 0; nt < 16; nt++) {
            float b = bias[nt * 16 + m];
            floatx4 bv = {b, b, b, b};
            av[nt] = bv; at[nt] = zero4;
        }
#pragma unroll
        for (int kt = 0; kt < 2; kt++) {
            short8 a_v = kt ? z1 : z0;
            short8 a_t = kt ? e1 : e0;
#pragma unroll
            for (int nt = 0; nt < 16; nt++) {
                short8 b = wb[(kt * 16 + nt) * 64 + lane];
                av[nt] = __builtin_amdgcn_mfma_f32_16x16x32_bf16(a_v, b, av[nt], 0, 0, 0);
                at[nt] = __builtin_amdgcn_mfma_f32_16x16x32_bf16(a_t, b, at[nt], 0, 0, 0);
            }
        }
    }
    act_transpose(av, at, Av, At, tbs, m, kq);

    // ---------------- layers 2,3: K=256 (8 kt), N=256 ----------------
#pragma unroll 1
    for (int layer = 0; layer < 2; layer++) {
        const short8* wb = (const short8*)(ws + (layer ? W3OFF : W2OFF));
        const float* bb = bias + 256 + layer * 256;
#pragma unroll
        for (int nt = 0; nt < 16; nt++) {
            float b = bb[nt * 16 + m];
            floatx4 bv = {b, b, b, b};
            av[nt] = bv; at[nt] = zero4;
        }
#pragma unroll
        for (int kt = 0; kt < 8; kt++) {
#pragma unroll
            for (int nt = 0; nt < 16; nt++) {
                short8 b = wb[(kt * 16 + nt) * 64 + lane];
                av[nt] = __builtin_amdgcn_mfma_f32_16x16x32_bf16(Av[kt], b, av[nt], 0, 0, 0);
                at[nt] = __builtin_amdgcn_mfma_f32_16x16x32_bf16(At[kt], b, at[nt], 0, 0, 0);
            }
        }
        act_transpose(av, at, Av, At, tbs, m, kq);
    }

    // ---------------- layer 4: K=256 (8 kt), N=64 ----------------
    floatx4 a4v[4], a4t[4];
    {
        const short8* wb = (const short8*)(ws + W4OFF);
#pragma unroll
        for (int nt = 0; nt < 4; nt++) {
            float b = bias[768 + nt * 16 + m];
            floatx4 bv = {b, b, b, b};
            a4v[nt] = bv; a4t[nt] = zero4;
        }
#pragma unroll
        for (int kt = 0; kt < 8; kt++) {
#pragma unroll
            for (int nt = 0; nt < 4; nt++) {
                short8 b = wb[(kt * 4 + nt) * 64 + lane];
                a4v[nt] = __builtin_amdgcn_mfma_f32_16x16x32_bf16(Av[kt], b, a4v[nt], 0, 0, 0);
                a4t[nt] = __builtin_amdgcn_mfma_f32_16x16x32_bf16(At[kt], b, a4t[nt], 0, 0, 0);
            }
        }
    }

    // Jeps: C->A layout via scratch, dot with eps fragments
#pragma unroll
    for (int nt = 0; nt < 4; nt++)
#pragma unroll
        for (int i = 0; i < 4; i++)
            tbf[(kq * 4 + i) * TBFSTR + nt * 16 + m] = a4t[nt][i];
    float div = 0.f;
#pragma unroll
    for (int kt2 = 0; kt2 < 2; kt2++) {
#pragma unroll
        for (int jj = 0; jj < 8; jj += 4) {
            floatx4 jv = *(const floatx4*)&tbf[m * TBFSTR + kt2 * 32 + kq * 8 + jj];
            div += jv.x * ef[kt2 * 8 + jj]     + jv.y * ef[kt2 * 8 + jj + 1]
                 + jv.z * ef[kt2 * 8 + jj + 2] + jv.w * ef[kt2 * 8 + jj + 3];
        }
    }
    div += __shfl_xor(div, 16, 64);
    div += __shfl_xor(div, 32, 64);

    // dz -> scratch for the caller to read in frag layout
#pragma unroll
    for (int nt = 0; nt < 4; nt++)
#pragma unroll
        for (int i = 0; i < 4; i++)
            tbf[(kq * 4 + i) * TBFSTR + nt * 16 + m] = a4v[nt][i];
    return div;
}

__global__ void __launch_bounds__(256, 2)
cnf_main(const float* __restrict__ x, const float* __restrict__ eps,
         const char* __restrict__ ws, float* __restrict__ out) {
    extern __shared__ char smem[];
    const int tid  = threadIdx.x;
    const int lane = tid & 63;
    const int wave = tid >> 6;
    const int m  = lane & 15, kq = lane >> 4;
    const int row = blockIdx.x * 64 + wave * 16 + m;
    short* tbs = (short*)(smem + wave * WAVE_LDS);
    float* tbf = (float*)tbs;
    short* kb  = (short*)(smem + wave * WAVE_LDS + KSLOTOFF);

    float y[16], ef[16];
#pragma unroll
    for (int kt = 0; kt < 2; kt++)
#pragma unroll
        for (int q = 0; q < 2; q++) {
            floatx4 vx = *(const floatx4*)(x   + row * DIM + kt * 32 + kq * 8 + q * 4);
            floatx4 ve = *(const floatx4*)(eps + row * DIM + kt * 32 + kq * 8 + q * 4);
#pragma unroll
            for (int j = 0; j < 4; j++) {
                y[kt * 8 + q * 4 + j]  = vx[j];
                ef[kt * 8 + q * 4 + j] = ve[j];
            }
        }
    short8 e0, e1;
#pragma unroll
    for (int j = 0; j < 8; j++) { e0[j] = f2bf(ef[j]); e1[j] = f2bf(ef[8 + j]); }

    float ylogp = 0.f;
    float K[16], zs[16];
    short8 z0, z1;

    auto pack2 = [&](const float* v) {
#pragma unroll
        for (int j = 0; j < 8; j++) { z0[j] = f2bf(v[j]); z1[j] = f2bf(v[8 + j]); }
    };
    auto readk = [&]() {
#pragma unroll
        for (int kt = 0; kt < 2; kt++) {
            floatx4 r0 = *(const floatx4*)&tbf[m * TBFSTR + kt * 32 + kq * 8];
            floatx4 r1 = *(const floatx4*)&tbf[m * TBFSTR + kt * 32 + kq * 8 + 4];
#pragma unroll
            for (int j = 0; j < 4; j++) { K[kt * 8 + j] = r0[j]; K[kt * 8 + 4 + j] = r1[j]; }
        }
    };
    auto storek = [&](int s) {
        short8 lo, hi;
#pragma unroll
        for (int j = 0; j < 8; j++) { lo[j] = f2bf(K[j]); hi[j] = f2bf(K[8 + j]); }
        *(short8*)&kb[s * 1024 + lane * 16]     = lo;
        *(short8*)&kb[s * 1024 + lane * 16 + 8] = hi;
    };
    auto addk = [&](int s, float c, float* dst) {
        short8 lo = *(const short8*)&kb[s * 1024 + lane * 16];
        short8 hi = *(const short8*)&kb[s * 1024 + lane * 16 + 8];
#pragma unroll
        for (int j = 0; j < 8; j++) {
            dst[j]     += c * bf2f(lo[j]);
            dst[8 + j] += c * bf2f(hi[j]);
        }
    };

#pragma unroll 1
    for (int step = 0; step < 4; step++) {
        pack2(y);
        const float d1 = feval(z0, z1, e0, e1, ef, ws, tbs);
        readk(); storek(0);
#pragma unroll
        for (int i = 0; i < 16; i++) zs[i] = y[i] + 0.05f * K[i];
        pack2(zs);
        const float d2 = feval(z0, z1, e0, e1, ef, ws, tbs);
        readk(); storek(1);
        (void)d2;
#pragma unroll
        for (int i = 0; i < 16; i++) zs[i] = y[i] + 0.05625f * K[i];
        addk(0, 0.01875f, zs);
        pack2(zs);
        const float d3 = feval(z0, z1, e0, e1, ef, ws, tbs);
        readk(); storek(2);
#pragma unroll
        for (int i = 0; i < 16; i++) zs[i] = y[i] + 0.888888889f * K[i];
        addk(0, 0.244444444f, zs); addk(1, -0.933333333f, zs);
        pack2(zs);
        const float d4 = feval(z0, z1, e0, e1, ef, ws, tbs);
        readk(); storek(3);
#pragma unroll
        for (int i = 0; i < 16; i++) zs[i] = y[i] - 0.072702332f * K[i];
        addk(0, 0.738149672f, zs); addk(1, -2.898948331f, zs); addk(2, 2.455723213f, zs);
        pack2(zs);
        const float d5 = feval(z0, z1, e0, e1, ef, ws, tbs);
        readk(); storek(4);
#pragma unroll
        for (int i = 0; i < 16; i++) zs[i] = y[i] - 0.068382826f * K[i];
        addk(0, 0.711568813f, zs); addk(1, -2.689393939f, zs);
        addk(2, 2.226605679f, zs); addk(3, 0.069602273f, zs);
        pack2(zs);
        const float d6 = feval(z0, z1, e0, e1, ef, ws, tbs);
        readk();   // K = k6, consumed immediately (never stored)
#pragma unroll
        for (int i = 0; i < 16; i++) y[i] += 0.032738095f * K[i];
        addk(0, 0.022786458f, y); addk(2, 0.112309075f, y);
        addk(3, 0.162760417f, y); addk(4, -0.080593989f, y);
        ylogp -= 0.022786458f * d1 + 0.112309075f * d3 + 0.162760417f * d4
               - 0.080593989f * d5 + 0.032738095f * d6;
    }

    float nrm = 0.f;
#pragma unroll
    for (int i = 0; i < 16; i++) nrm += y[i] * y[i];
    nrm += __shfl_xor(nrm, 16, 64);
    nrm += __shfl_xor(nrm, 32, 64);
    float res = -0.5f * nrm - LOG2PI_HALF_SUM - ylogp;
    if (lane < 16) out[blockIdx.x * 64 + wave * 16 + lane] = res;
}

// ---- weight pre-shuffle: fp32 [N][K] -> bf16 fragment-linear ----
// frag = ktile*NT + ntile; lane l holds W[ntile*16+(l&15)][ktile*32+(l>>4)*8 + 0..7]
__global__ void prep_w(const float* __restrict__ W, short* __restrict__ outp,
                       int K, int NT, int KT) {
    int slot  = blockIdx.x * 256 + threadIdx.x;
    int total = KT * NT * 64;
    if (slot >= total) return;
    int lane  = slot & 63, frag = slot >> 6;
    int ntile = frag % NT, ktile = frag / NT;
    int n = ntile * 16 + (lane & 15);
    int k = ktile * 32 + (lane >> 4) * 8;
    short8 v;
#pragma unroll
    for (int j = 0; j < 8; j++) v[j] = f2bf(W[n * K + k + j]);
    *(short8*)(outp + slot * 8) = v;
}

__global__ void prep_b(const float* __restrict__ b1, const float* __restrict__ b2,
                       const float* __restrict__ b3, const float* __restrict__ b4,
                       float* __restrict__ dst) {
    int i = blockIdx.x * 256 + threadIdx.x;
    if (i < 256)      dst[i] = b1[i];
    else if (i < 512) dst[i] = b2[i - 256];
    else if (i < 768) dst[i] = b3[i - 512];
    else if (i < 832) dst[i] = b4[i - 768];
}

extern "C" void kernel_launch(void* const* d_in, const int* in_sizes, int n_in,
                              void* d_out, int out_size, void* d_ws, size_t ws_size,
                              hipStream_t stream) {
    const float* x   = (const float*)d_in[0];
    const float* eps = (const float*)d_in[1];
    const float* W1  = (const float*)d_in[2];
    const float* b1  = (const float*)d_in[3];
    const float* W2  = (const float*)d_in[4];
    const float* b2  = (const float*)d_in[5];
    const float* W3  = (const float*)d_in[6];
    const float* b3  = (const float*)d_in[7];
    const float* W4  = (const float*)d_in[8];
    const float* b4  = (const float*)d_in[9];
    char*  ws  = (char*)d_ws;
    float* out = (float*)d_out;

    prep_w<<<(2 * 16 * 64 + 255) / 256, 256, 0, stream>>>(W1, (short*)(ws + W1OFF), 64, 16, 2);
    prep_w<<<(8 * 16 * 64 + 255) / 256, 256, 0, stream>>>(W2, (short*)(ws + W2OFF), 256, 16, 8);
    prep_w<<<(8 * 16 * 64 + 255) / 256, 256, 0, stream>>>(W3, (short*)(ws + W3OFF), 256, 16, 8);
    prep_w<<<(8 * 4 * 64 + 255) / 256, 256, 0, stream>>>(W4, (short*)(ws + W4OFF), 256, 4, 8);
    prep_b<<<4, 256, 0, stream>>>(b1, b2, b3, b4, (float*)(ws + BOFF));

    cnf_main<<<BATCH / 64, 256, SMEM_BYTES, stream>>>(x, eps, ws, out);
}